// Round 5
// baseline (466.558 us; speedup 1.0000x reference)
//
#include <hip/hip_runtime.h>
#include <hip/hip_bf16.h>
#include <cstdint>
#include <cstddef>

#define N_NODES 50000
#define N_EDGES 300000
#define DIM     256
#define KTOT    768   // concatenated K: [agg*norm | h | prev_h]
#define N_RELS  500

#define SCAN_BLK  256
#define SCAN_NBLK ((N_NODES + SCAN_BLK - 1) / SCAN_BLK)   // 196

typedef unsigned short u16;
typedef __attribute__((ext_vector_type(8))) short short8v;   // 8 bf16 = 4 VGPRs (MFMA A/B frag)
typedef __attribute__((ext_vector_type(4))) float float4v;   // MFMA C/D frag

static __device__ __forceinline__ u16 f2bf(float f) {
    union { float f; unsigned u; } v; v.f = f;
    unsigned u = v.u;
    unsigned r = u + 0x7FFFu + ((u >> 16) & 1u);  // RNE
    return (u16)(r >> 16);
}

// ---------------- K2: build Wt[d][k] = Wseg[k%256][d] (bf16, B^T layout) ----------------
__global__ void wt_kernel(const float* __restrict__ Wn, const float* __restrict__ Wl,
                          const float* __restrict__ Wsc, u16* __restrict__ Wt) {
    int k = blockIdx.x;    // 0..767
    int d = threadIdx.x;   // 0..255
    const float* W = (k < 256) ? Wn : ((k < 512) ? Wl : Wsc);
    int kk = k & 255;
    Wt[(size_t)d * KTOT + k] = f2bf(W[kk * DIM + d]);
}

// ---------------- K3: in-degree histogram ----------------
__global__ void hist_kernel(const int* __restrict__ dstv, int* __restrict__ deg) {
    int e = blockIdx.x * 256 + threadIdx.x;
    if (e < N_EDGES) atomicAdd(&deg[dstv[e]], 1);
}

// ---------------- K4a: per-block scan of deg ----------------
__global__ void scanA_kernel(const int* __restrict__ deg, int* __restrict__ excl_local,
                             int* __restrict__ block_sum) {
    __shared__ int sdata[SCAN_BLK];
    int t = threadIdx.x, i = blockIdx.x * SCAN_BLK + t;
    int v = (i < N_NODES) ? deg[i] : 0;
    sdata[t] = v;
    __syncthreads();
    for (int off = 1; off < SCAN_BLK; off <<= 1) {
        int u = (t >= off) ? sdata[t - off] : 0;
        __syncthreads();
        sdata[t] += u;
        __syncthreads();
    }
    if (i < N_NODES) excl_local[i] = sdata[t] - v;
    if (t == SCAN_BLK - 1) block_sum[blockIdx.x] = sdata[t];
}

// ---------------- K4b: scan 196 block sums (1 block) ----------------
__global__ void scanB_kernel(const int* __restrict__ block_sum, int* __restrict__ block_base,
                             int* __restrict__ offsets) {
    __shared__ int sdata[SCAN_NBLK];
    int t = threadIdx.x;
    int v = (t < SCAN_NBLK) ? block_sum[t] : 0;
    if (t < SCAN_NBLK) sdata[t] = v;
    __syncthreads();
    for (int off = 1; off < SCAN_NBLK; off <<= 1) {
        int u = (t >= off && t < SCAN_NBLK) ? sdata[t - off] : 0;
        __syncthreads();
        if (t < SCAN_NBLK) sdata[t] += u;
        __syncthreads();
    }
    if (t < SCAN_NBLK) block_base[t] = sdata[t] - v;
    if (t == SCAN_NBLK - 1) offsets[N_NODES] = sdata[t];
}

// ---------------- K4c: combine -> offsets, cursor ----------------
__global__ void scanC_kernel(const int* __restrict__ excl_local, const int* __restrict__ block_base,
                             int* __restrict__ offsets, int* __restrict__ cursor) {
    int i = blockIdx.x * SCAN_BLK + threadIdx.x;
    if (i < N_NODES) {
        int e = block_base[blockIdx.x] + excl_local[i];
        offsets[i] = e; cursor[i] = e;
    }
}

// ---------------- K5: scatter edges into CSR slots (packed src*500+et) ----------------
__global__ void scatter_kernel(const int* __restrict__ src, const int* __restrict__ dstv,
                               const int* __restrict__ et, int* __restrict__ cursor,
                               unsigned* __restrict__ esee) {
    int e = blockIdx.x * 256 + threadIdx.x;
    if (e >= N_EDGES) return;
    int d = dstv[e];
    int pos = atomicAdd(&cursor[d], 1);
    esee[pos] = (unsigned)src[e] * N_RELS + (unsigned)et[e];
}

// ---------------- K6: wave-per-node gather-reduce -> Xa = bf16(agg*norm); worklist ----------------
__global__ void agg_kernel(const float* __restrict__ h, const float* __restrict__ emb,
                           const float* __restrict__ norm, const int* __restrict__ offsets,
                           const unsigned* __restrict__ esee,
                           u16* __restrict__ Xa, int* __restrict__ wl_count, int* __restrict__ wl) {
    int wave = (blockIdx.x * 256 + threadIdx.x) >> 6;
    int lane = threadIdx.x & 63;
    if (wave >= N_NODES) return;
    int n = wave;
    int s0 = offsets[n], s1 = offsets[n + 1];
    int c4 = lane * 4;
    float4 acc = make_float4(0.f, 0.f, 0.f, 0.f);
    for (int e = s0; e < s1; e++) {
        unsigned v = esee[e];
        unsigned s = v / N_RELS;          // magic-mul
        unsigned t = v - s * N_RELS;
        float4 hv = *(const float4*)(h   + (size_t)s * DIM + c4);
        float4 ev = *(const float4*)(emb + (size_t)t * DIM + c4);
        acc.x += hv.x + ev.x; acc.y += hv.y + ev.y;
        acc.z += hv.z + ev.z; acc.w += hv.w + ev.w;
    }
    float nr = norm[n];
    u16 o[4] = { f2bf(acc.x * nr), f2bf(acc.y * nr), f2bf(acc.z * nr), f2bf(acc.w * nr) };
    *(ushort4*)(Xa + (size_t)n * DIM + c4) = *(const ushort4*)o;
    if (lane == 0 && s1 == s0) { int idx = atomicAdd(wl_count, 1); wl[idx] = n; }
}

// ---------------- K7: fused MFMA GEMM + epilogue, register-prefetch pipeline ----------------
// Block: 256 thr = 4 waves. Tile: 64 nodes x 256 cols (wave w: cols [w*64, +64)).
// K: kt 0..11 over [Xa bf16 | h fp32->bf16 | prev_h fp32->bf16] vs Wt rows.
// acc1 = kt 0..7 (agg*norm@Wn + h@Wl), acc2 = kt 8..11 (prev_h@Wsc).
// Pipeline: global loads for kt+1 issue right after the staging barrier of kt,
// consumed at the top of iteration kt+1 -> HBM latency hidden behind MFMA+ds_read.
#define LDSP 72   // 64 + 8 bf16 pad: row stride 144B -> benign bank aliasing
__launch_bounds__(256, 2)
__global__ void gemm_kernel(const u16* __restrict__ Xa, const u16* __restrict__ Wt,
                            const float* __restrict__ h, const float* __restrict__ prev_h,
                            const float* __restrict__ bias, float* __restrict__ out) {
    __shared__ u16 Xs[64 * LDSP];    //  9216 B
    __shared__ u16 Ws[256 * LDSP];   // 36864 B
    int tid = threadIdx.x;
    int wave = tid >> 6, lane = tid & 63, q = lane >> 4, m16 = lane & 15;
    int wn = wave * 64;
    int m0 = blockIdx.x * 64;

    float4v acc1[4][4], acc2[4][4];
#pragma unroll
    for (int i = 0; i < 4; i++)
#pragma unroll
        for (int j = 0; j < 4; j++) { acc1[i][j] = (float4v)0.f; acc2[i][j] = (float4v)0.f; }

    // staging maps
    int xrow = tid >> 2, xcol = (tid & 3) * 16;   // X: 64 rows, 32 B (16 bf16) per thread
    int wp   = tid & 7,  wd   = tid >> 3;         // W: 8x16B per row, 32 rows/round, 8 rounds
    int grow = min(m0 + xrow, N_NODES - 1);

    uint4  xreg[2];   // bf16 staging (kt<4)
    float4 freg[4];   // fp32 staging (kt>=4), converted at store time
    uint4  wreg[8];

    // prefetch kt = 0
    {
        const u16* p = Xa + (size_t)grow * DIM + xcol;
        xreg[0] = *(const uint4*)p;
        xreg[1] = *(const uint4*)(p + 8);
#pragma unroll
        for (int it = 0; it < 8; it++)
            wreg[it] = *(const uint4*)(Wt + (size_t)(wd + it * 32) * KTOT + wp * 8);
    }

    for (int kt = 0; kt < 12; kt++) {
        // ---- store prefetched regs to LDS ----
        if (kt < 4) {
            *(uint4*)(&Xs[xrow * LDSP + xcol])     = xreg[0];
            *(uint4*)(&Xs[xrow * LDSP + xcol + 8]) = xreg[1];
        } else {
            u16 o[16];
#pragma unroll
            for (int j = 0; j < 4; j++) {
                o[j*4+0] = f2bf(freg[j].x); o[j*4+1] = f2bf(freg[j].y);
                o[j*4+2] = f2bf(freg[j].z); o[j*4+3] = f2bf(freg[j].w);
            }
            *(uint4*)(&Xs[xrow * LDSP + xcol])     = ((const uint4*)o)[0];
            *(uint4*)(&Xs[xrow * LDSP + xcol + 8]) = ((const uint4*)o)[1];
        }
#pragma unroll
        for (int it = 0; it < 8; it++)
            *(uint4*)(&Ws[(wd + it * 32) * LDSP + wp * 8]) = wreg[it];
        __syncthreads();

        // ---- issue global loads for kt+1 (consumed next iteration) ----
        if (kt < 11) {
            int nk = kt + 1;
            int koff = (nk & 3) * 64;
            if (nk < 4) {
                const u16* p = Xa + (size_t)grow * DIM + koff + xcol;
                xreg[0] = *(const uint4*)p;
                xreg[1] = *(const uint4*)(p + 8);
            } else {
                const float* F = (nk < 8) ? h : prev_h;
                const float* p = F + (size_t)grow * DIM + koff + xcol;
#pragma unroll
                for (int j = 0; j < 4; j++)
                    freg[j] = *(const float4*)(p + j * 4);
            }
#pragma unroll
            for (int it = 0; it < 8; it++)
                wreg[it] = *(const uint4*)(Wt + (size_t)(wd + it * 32) * KTOT + nk * 64 + wp * 8);
        }

        // ---- compute kt ----
#pragma unroll
        for (int kk = 0; kk < 2; kk++) {
            short8v af[4], bfr[4];
#pragma unroll
            for (int mi = 0; mi < 4; mi++)
                af[mi] = *(const short8v*)(&Xs[(mi * 16 + m16) * LDSP + kk * 32 + q * 8]);
#pragma unroll
            for (int ni = 0; ni < 4; ni++)
                bfr[ni] = *(const short8v*)(&Ws[(wn + ni * 16 + m16) * LDSP + kk * 32 + q * 8]);
            if (kt < 8) {
#pragma unroll
                for (int mi = 0; mi < 4; mi++)
#pragma unroll
                    for (int ni = 0; ni < 4; ni++)
                        acc1[mi][ni] = __builtin_amdgcn_mfma_f32_16x16x32_bf16(
                            af[mi], bfr[ni], acc1[mi][ni], 0, 0, 0);
            } else {
#pragma unroll
                for (int mi = 0; mi < 4; mi++)
#pragma unroll
                    for (int ni = 0; ni < 4; ni++)
                        acc2[mi][ni] = __builtin_amdgcn_mfma_f32_16x16x32_bf16(
                            af[mi], bfr[ni], acc2[mi][ni], 0, 0, 0);
            }
        }
        __syncthreads();
    }

    // epilogue: C/D layout col=lane&15, row=q*4+reg  [measured m89]
#pragma unroll
    for (int mi = 0; mi < 4; mi++) {
#pragma unroll
        for (int ni = 0; ni < 4; ni++) {
            int d = wn + ni * 16 + m16;
            float b = bias[d];
#pragma unroll
            for (int r = 0; r < 4; r++) {
                int node = m0 + mi * 16 + q * 4 + r;
                if (node < N_NODES) {
                    float S  = acc2[mi][ni][r] + b;
                    float sw = 1.f / (1.f + __expf(-S));
                    float ph = prev_h[(size_t)node * DIM + d];
                    float v  = sw * acc1[mi][ni][r] + (1.f - sw) * ph;
                    out[(size_t)node * DIM + d] = fmaxf(v, 0.f);
                }
            }
        }
    }
}

// ---------------- K8: fixup for in_deg==0 nodes (evolve_loop_weight path, exact fp32) --------
__global__ void fixup_kernel(const float* __restrict__ h, const float* __restrict__ prev_h,
                             const float* __restrict__ We, const float* __restrict__ Wsc,
                             const float* __restrict__ bias, const int* __restrict__ wl_count,
                             const int* __restrict__ wl, float* __restrict__ out) {
    __shared__ float ph[DIM], hh[DIM];
    int d = threadIdx.x;
    int cnt = *wl_count;
    for (int i = blockIdx.x; i < cnt; i += gridDim.x) {
        int n = wl[i];
        ph[d] = prev_h[(size_t)n * DIM + d];
        hh[d] = h[(size_t)n * DIM + d];
        __syncthreads();
        float s = 0.f, l = 0.f;
        for (int k = 0; k < DIM; k++) {
            s += ph[k] * Wsc[k * DIM + d];
            l += hh[k] * We[k * DIM + d];
        }
        float sw = 1.f / (1.f + __expf(-(s + bias[d])));
        float v = sw * l + (1.f - sw) * ph[d];
        out[(size_t)n * DIM + d] = fmaxf(v, 0.f);
        __syncthreads();
    }
}

extern "C" void kernel_launch(void* const* d_in, const int* in_sizes, int n_in,
                              void* d_out, int out_size, void* d_ws, size_t ws_size,
                              hipStream_t stream) {
    const float* h      = (const float*)d_in[0];
    const float* prev_h = (const float*)d_in[1];
    const float* emb    = (const float*)d_in[2];
    const float* norm   = (const float*)d_in[3];
    const float* Wn     = (const float*)d_in[4];
    const float* Wl     = (const float*)d_in[5];
    const float* We     = (const float*)d_in[6];
    const float* Wsc    = (const float*)d_in[7];
    const float* bias   = (const float*)d_in[8];
    const int*   src    = (const int*)d_in[9];
    const int*   dstv   = (const int*)d_in[10];
    const int*   et     = (const int*)d_in[11];
    float* out = (float*)d_out;

    char* ws = (char*)d_ws;
    size_t off = 0;
    auto alloc = [&](size_t bytes) -> char* {
        char* p = ws + off; off += (bytes + 255) & ~(size_t)255; return p;
    };
    u16* Xa      = (u16*)alloc((size_t)N_NODES * DIM * 2);
    u16* Wt      = (u16*)alloc((size_t)DIM * KTOT * 2);
    int* deg     = (int*)alloc((size_t)N_NODES * 4);
    int* wlcnt   = (int*)alloc(16);
    int* wl      = (int*)alloc((size_t)N_NODES * 4);
    int* offsets = (int*)alloc((size_t)(N_NODES + 1) * 4);
    int* cursor  = (int*)alloc((size_t)N_NODES * 4);
    unsigned* esee = (unsigned*)alloc((size_t)N_EDGES * 4);
    int* excl    = (int*)alloc((size_t)N_NODES * 4);
    int* bsum    = (int*)alloc((size_t)SCAN_NBLK * 4);
    int* bbase   = (int*)alloc((size_t)SCAN_NBLK * 4);

    hipMemsetAsync(deg, 0, (size_t)N_NODES * 4, stream);
    hipMemsetAsync(wlcnt, 0, 4, stream);

    wt_kernel<<<KTOT, 256, 0, stream>>>(Wn, Wl, Wsc, Wt);
    hist_kernel<<<(N_EDGES + 255) / 256, 256, 0, stream>>>(dstv, deg);
    scanA_kernel<<<SCAN_NBLK, SCAN_BLK, 0, stream>>>(deg, excl, bsum);
    scanB_kernel<<<1, SCAN_BLK, 0, stream>>>(bsum, bbase, offsets);
    scanC_kernel<<<SCAN_NBLK, SCAN_BLK, 0, stream>>>(excl, bbase, offsets, cursor);
    scatter_kernel<<<(N_EDGES + 255) / 256, 256, 0, stream>>>(src, dstv, et, cursor, esee);
    agg_kernel<<<(N_NODES + 3) / 4, 256, 0, stream>>>(h, emb, norm, offsets, esee, Xa, wlcnt, wl);
    gemm_kernel<<<(N_NODES + 63) / 64, 256, 0, stream>>>(Xa, Wt, h, prev_h, bias, out);
    fixup_kernel<<<256, 256, 0, stream>>>(h, prev_h, We, Wsc, bias, wlcnt, wl, out);
}

// Round 6
// 346.837 us; speedup vs baseline: 1.3452x; 1.3452x over previous
//
#include <hip/hip_runtime.h>
#include <hip/hip_bf16.h>
#include <cstdint>
#include <cstddef>

#define N_NODES 50000
#define N_EDGES 300000
#define DIM     256
#define KTOT    768   // concatenated K: [agg*norm | h | prev_h]
#define N_RELS  500

#define SCAN_BLK  256
#define SCAN_NBLK ((N_NODES + SCAN_BLK - 1) / SCAN_BLK)   // 196

typedef unsigned short u16;
typedef __attribute__((ext_vector_type(8))) short short8v;   // 8 bf16 = 4 VGPRs (MFMA A/B frag)
typedef __attribute__((ext_vector_type(4))) float float4v;   // MFMA C/D frag

static __device__ __forceinline__ u16 f2bf(float f) {
    union { float f; unsigned u; } v; v.f = f;
    unsigned u = v.u;
    unsigned r = u + 0x7FFFu + ((u >> 16) & 1u);  // RNE
    return (u16)(r >> 16);
}
static __device__ __forceinline__ float bf2f(u16 b) {
    union { unsigned u; float f; } v; v.u = ((unsigned)b) << 16; return v.f;
}

// ---------------- K1: h -> Xh (bf16), emb -> embb (bf16) ----------------
__global__ void conv_kernel(const float* __restrict__ h, const float* __restrict__ emb,
                            u16* __restrict__ Xh, u16* __restrict__ embb) {
    int i = blockIdx.x * blockDim.x + threadIdx.x;
    int e0 = i * 8;
    if (e0 >= (N_NODES + N_RELS) * DIM) return;
    const float* src; u16* dst; int off;
    if (e0 < N_NODES * DIM) { src = h;   dst = Xh;   off = e0; }
    else                    { src = emb; dst = embb; off = e0 - N_NODES * DIM; }
    float4 a = *(const float4*)(src + off);
    float4 b = *(const float4*)(src + off + 4);
    u16 o[8] = { f2bf(a.x), f2bf(a.y), f2bf(a.z), f2bf(a.w),
                 f2bf(b.x), f2bf(b.y), f2bf(b.z), f2bf(b.w) };
    *(uint4*)(dst + off) = *(const uint4*)o;
}

// ---------------- K2: build Wt[d][k] = Wseg[k%256][d] (bf16, B^T layout) ----------------
__global__ void wt_kernel(const float* __restrict__ Wn, const float* __restrict__ Wl,
                          const float* __restrict__ Wsc, u16* __restrict__ Wt) {
    int k = blockIdx.x;    // 0..767
    int d = threadIdx.x;   // 0..255
    const float* W = (k < 256) ? Wn : ((k < 512) ? Wl : Wsc);
    int kk = k & 255;
    Wt[(size_t)d * KTOT + k] = f2bf(W[kk * DIM + d]);
}

// ---------------- K3: in-degree histogram ----------------
__global__ void hist_kernel(const int* __restrict__ dstv, int* __restrict__ deg) {
    int e = blockIdx.x * 256 + threadIdx.x;
    if (e < N_EDGES) atomicAdd(&deg[dstv[e]], 1);
}

// ---------------- K4a: per-block scan of deg ----------------
__global__ void scanA_kernel(const int* __restrict__ deg, int* __restrict__ excl_local,
                             int* __restrict__ block_sum) {
    __shared__ int sdata[SCAN_BLK];
    int t = threadIdx.x, i = blockIdx.x * SCAN_BLK + t;
    int v = (i < N_NODES) ? deg[i] : 0;
    sdata[t] = v;
    __syncthreads();
    for (int off = 1; off < SCAN_BLK; off <<= 1) {
        int u = (t >= off) ? sdata[t - off] : 0;
        __syncthreads();
        sdata[t] += u;
        __syncthreads();
    }
    if (i < N_NODES) excl_local[i] = sdata[t] - v;
    if (t == SCAN_BLK - 1) block_sum[blockIdx.x] = sdata[t];
}

// ---------------- K4b: scan 196 block sums (1 block) ----------------
__global__ void scanB_kernel(const int* __restrict__ block_sum, int* __restrict__ block_base,
                             int* __restrict__ offsets) {
    __shared__ int sdata[SCAN_NBLK];
    int t = threadIdx.x;
    int v = (t < SCAN_NBLK) ? block_sum[t] : 0;
    if (t < SCAN_NBLK) sdata[t] = v;
    __syncthreads();
    for (int off = 1; off < SCAN_NBLK; off <<= 1) {
        int u = (t >= off && t < SCAN_NBLK) ? sdata[t - off] : 0;
        __syncthreads();
        if (t < SCAN_NBLK) sdata[t] += u;
        __syncthreads();
    }
    if (t < SCAN_NBLK) block_base[t] = sdata[t] - v;
    if (t == SCAN_NBLK - 1) offsets[N_NODES] = sdata[t];
}

// ---------------- K4c: combine -> offsets, cursor ----------------
__global__ void scanC_kernel(const int* __restrict__ excl_local, const int* __restrict__ block_base,
                             int* __restrict__ offsets, int* __restrict__ cursor) {
    int i = blockIdx.x * SCAN_BLK + threadIdx.x;
    if (i < N_NODES) {
        int e = block_base[blockIdx.x] + excl_local[i];
        offsets[i] = e; cursor[i] = e;
    }
}

// ---------------- K5: scatter edges into CSR slots (packed src*500+et) ----------------
__global__ void scatter_kernel(const int* __restrict__ src, const int* __restrict__ dstv,
                               const int* __restrict__ et, int* __restrict__ cursor,
                               unsigned* __restrict__ esee) {
    int e = blockIdx.x * 256 + threadIdx.x;
    if (e >= N_EDGES) return;
    int d = dstv[e];
    int pos = atomicAdd(&cursor[d], 1);
    esee[pos] = (unsigned)src[e] * N_RELS + (unsigned)et[e];
}

// ---------------- K6: wave-per-node gather-reduce (bf16 sources) -> Xa ----------------
__global__ void agg_kernel(const u16* __restrict__ Xh, const u16* __restrict__ embb,
                           const float* __restrict__ norm, const int* __restrict__ offsets,
                           const unsigned* __restrict__ esee,
                           u16* __restrict__ Xa, int* __restrict__ wl_count, int* __restrict__ wl) {
    int wave = (blockIdx.x * 256 + threadIdx.x) >> 6;
    int lane = threadIdx.x & 63;
    if (wave >= N_NODES) return;
    int n = wave;
    int s0 = offsets[n], s1 = offsets[n + 1];
    int c4 = lane * 4;
    float4 acc = make_float4(0.f, 0.f, 0.f, 0.f);
    for (int e = s0; e < s1; e++) {
        unsigned v = esee[e];
        unsigned s = v / N_RELS;          // magic-mul
        unsigned t = v - s * N_RELS;
        ushort4 hv = *(const ushort4*)(Xh   + (size_t)s * DIM + c4);
        ushort4 ev = *(const ushort4*)(embb + (size_t)t * DIM + c4);
        acc.x += bf2f(hv.x) + bf2f(ev.x);
        acc.y += bf2f(hv.y) + bf2f(ev.y);
        acc.z += bf2f(hv.z) + bf2f(ev.z);
        acc.w += bf2f(hv.w) + bf2f(ev.w);
    }
    float nr = norm[n];
    u16 o[4] = { f2bf(acc.x * nr), f2bf(acc.y * nr), f2bf(acc.z * nr), f2bf(acc.w * nr) };
    *(ushort4*)(Xa + (size_t)n * DIM + c4) = *(const ushort4*)o;
    if (lane == 0 && s1 == s0) { int idx = atomicAdd(wl_count, 1); wl[idx] = n; }
}

// ---------------- K7: fused MFMA GEMM + epilogue (R3 structure, transient staging) --------
// Block: 256 thr = 4 waves. Tile: 64 nodes x 256 cols (wave w: cols [w*64, +64)).
// K: kt 0..11 over [Xa | Xh | prev_h(fp32, converted transiently)] vs Wt rows.
// acc1 = kt 0..7 (agg*norm@Wn + h@Wl), acc2 = kt 8..11 (prev_h@Wsc).
// NOTE: no cross-iteration register residency — 128 acc regs + transient staging
// is the proven-fit budget at (256,2); prefetch regs spill (R5 post-mortem).
#define LDSP 72   // 64 + 8 bf16 pad: row stride 144B -> benign bank aliasing
__launch_bounds__(256, 2)
__global__ void gemm_kernel(const u16* __restrict__ Xa, const u16* __restrict__ Xh,
                            const u16* __restrict__ Wt, const float* __restrict__ prev_h,
                            const float* __restrict__ bias, float* __restrict__ out) {
    __shared__ u16 Xs[64 * LDSP];    //  9216 B
    __shared__ u16 Ws[256 * LDSP];   // 36864 B
    int tid = threadIdx.x;
    int wave = tid >> 6, lane = tid & 63, q = lane >> 4, m16 = lane & 15;
    int wn = wave * 64;
    int m0 = blockIdx.x * 64;

    float4v acc1[4][4], acc2[4][4];
#pragma unroll
    for (int i = 0; i < 4; i++)
#pragma unroll
        for (int j = 0; j < 4; j++) { acc1[i][j] = (float4v)0.f; acc2[i][j] = (float4v)0.f; }

    // staging maps
    int xr = tid >> 3, xc = (tid & 7) * 8;        // X: rows xr / xr+32, 8 bf16 each
    int wp = tid & 7,  wd = tid >> 3;             // W: 8x16B per row, 32 rows/round
    int xrow0 = min(m0 + xr, N_NODES - 1);
    int xrow1 = min(m0 + xr + 32, N_NODES - 1);

    for (int kt = 0; kt < 12; kt++) {
        int koff = (kt & 3) * 64;
        if (kt < 8) {
            const u16* Xsrc = (kt < 4) ? Xa : Xh;
            *(uint4*)(&Xs[xr * LDSP + xc]) =
                *(const uint4*)(Xsrc + (size_t)xrow0 * DIM + koff + xc);
            *(uint4*)(&Xs[(xr + 32) * LDSP + xc]) =
                *(const uint4*)(Xsrc + (size_t)xrow1 * DIM + koff + xc);
        } else {
            const float* p0 = prev_h + (size_t)xrow0 * DIM + koff + xc;
            const float* p1 = prev_h + (size_t)xrow1 * DIM + koff + xc;
            float4 a0 = *(const float4*)p0, b0 = *(const float4*)(p0 + 4);
            float4 a1 = *(const float4*)p1, b1 = *(const float4*)(p1 + 4);
            u16 o0[8] = { f2bf(a0.x), f2bf(a0.y), f2bf(a0.z), f2bf(a0.w),
                          f2bf(b0.x), f2bf(b0.y), f2bf(b0.z), f2bf(b0.w) };
            u16 o1[8] = { f2bf(a1.x), f2bf(a1.y), f2bf(a1.z), f2bf(a1.w),
                          f2bf(b1.x), f2bf(b1.y), f2bf(b1.z), f2bf(b1.w) };
            *(uint4*)(&Xs[xr * LDSP + xc])        = *(const uint4*)o0;
            *(uint4*)(&Xs[(xr + 32) * LDSP + xc]) = *(const uint4*)o1;
        }
#pragma unroll
        for (int it = 0; it < 8; it++) {
            int d = wd + it * 32;
            *(uint4*)(&Ws[d * LDSP + wp * 8]) =
                *(const uint4*)(Wt + (size_t)d * KTOT + kt * 64 + wp * 8);
        }
        __syncthreads();
#pragma unroll
        for (int kk = 0; kk < 2; kk++) {
            short8v af[4], bfr[4];
#pragma unroll
            for (int mi = 0; mi < 4; mi++)
                af[mi] = *(const short8v*)(&Xs[(mi * 16 + m16) * LDSP + kk * 32 + q * 8]);
#pragma unroll
            for (int ni = 0; ni < 4; ni++)
                bfr[ni] = *(const short8v*)(&Ws[(wn + ni * 16 + m16) * LDSP + kk * 32 + q * 8]);
            if (kt < 8) {
#pragma unroll
                for (int mi = 0; mi < 4; mi++)
#pragma unroll
                    for (int ni = 0; ni < 4; ni++)
                        acc1[mi][ni] = __builtin_amdgcn_mfma_f32_16x16x32_bf16(
                            af[mi], bfr[ni], acc1[mi][ni], 0, 0, 0);
            } else {
#pragma unroll
                for (int mi = 0; mi < 4; mi++)
#pragma unroll
                    for (int ni = 0; ni < 4; ni++)
                        acc2[mi][ni] = __builtin_amdgcn_mfma_f32_16x16x32_bf16(
                            af[mi], bfr[ni], acc2[mi][ni], 0, 0, 0);
            }
        }
        __syncthreads();
    }

    // epilogue: C/D layout col=lane&15, row=q*4+reg  [measured m89]
#pragma unroll
    for (int mi = 0; mi < 4; mi++) {
#pragma unroll
        for (int ni = 0; ni < 4; ni++) {
            int d = wn + ni * 16 + m16;
            float b = bias[d];
#pragma unroll
            for (int r = 0; r < 4; r++) {
                int node = m0 + mi * 16 + q * 4 + r;
                if (node < N_NODES) {
                    float S  = acc2[mi][ni][r] + b;
                    float sw = 1.f / (1.f + __expf(-S));
                    float ph = prev_h[(size_t)node * DIM + d];
                    float v  = sw * acc1[mi][ni][r] + (1.f - sw) * ph;
                    out[(size_t)node * DIM + d] = fmaxf(v, 0.f);
                }
            }
        }
    }
}

// ---------------- K8: fixup for in_deg==0 nodes (evolve_loop_weight path, exact fp32) --------
__global__ void fixup_kernel(const float* __restrict__ h, const float* __restrict__ prev_h,
                             const float* __restrict__ We, const float* __restrict__ Wsc,
                             const float* __restrict__ bias, const int* __restrict__ wl_count,
                             const int* __restrict__ wl, float* __restrict__ out) {
    __shared__ float ph[DIM], hh[DIM];
    int d = threadIdx.x;
    int cnt = *wl_count;
    for (int i = blockIdx.x; i < cnt; i += gridDim.x) {
        int n = wl[i];
        ph[d] = prev_h[(size_t)n * DIM + d];
        hh[d] = h[(size_t)n * DIM + d];
        __syncthreads();
        float s = 0.f, l = 0.f;
        for (int k = 0; k < DIM; k++) {
            s += ph[k] * Wsc[k * DIM + d];
            l += hh[k] * We[k * DIM + d];
        }
        float sw = 1.f / (1.f + __expf(-(s + bias[d])));
        float v = sw * l + (1.f - sw) * ph[d];
        out[(size_t)n * DIM + d] = fmaxf(v, 0.f);
        __syncthreads();
    }
}

extern "C" void kernel_launch(void* const* d_in, const int* in_sizes, int n_in,
                              void* d_out, int out_size, void* d_ws, size_t ws_size,
                              hipStream_t stream) {
    const float* h      = (const float*)d_in[0];
    const float* prev_h = (const float*)d_in[1];
    const float* emb    = (const float*)d_in[2];
    const float* norm   = (const float*)d_in[3];
    const float* Wn     = (const float*)d_in[4];
    const float* Wl     = (const float*)d_in[5];
    const float* We     = (const float*)d_in[6];
    const float* Wsc    = (const float*)d_in[7];
    const float* bias   = (const float*)d_in[8];
    const int*   src    = (const int*)d_in[9];
    const int*   dstv   = (const int*)d_in[10];
    const int*   et     = (const int*)d_in[11];
    float* out = (float*)d_out;

    char* ws = (char*)d_ws;
    size_t off = 0;
    auto alloc = [&](size_t bytes) -> char* {
        char* p = ws + off; off += (bytes + 255) & ~(size_t)255; return p;
    };
    u16* Xa      = (u16*)alloc((size_t)N_NODES * DIM * 2);
    u16* Xh      = (u16*)alloc((size_t)N_NODES * DIM * 2);
    u16* embb    = (u16*)alloc((size_t)N_RELS * DIM * 2);
    u16* Wt      = (u16*)alloc((size_t)DIM * KTOT * 2);
    int* deg     = (int*)alloc((size_t)N_NODES * 4);
    int* wlcnt   = (int*)alloc(16);
    int* wl      = (int*)alloc((size_t)N_NODES * 4);
    int* offsets = (int*)alloc((size_t)(N_NODES + 1) * 4);
    int* cursor  = (int*)alloc((size_t)N_NODES * 4);
    unsigned* esee = (unsigned*)alloc((size_t)N_EDGES * 4);
    int* excl    = (int*)alloc((size_t)N_NODES * 4);
    int* bsum    = (int*)alloc((size_t)SCAN_NBLK * 4);
    int* bbase   = (int*)alloc((size_t)SCAN_NBLK * 4);

    hipMemsetAsync(deg, 0, (size_t)N_NODES * 4, stream);
    hipMemsetAsync(wlcnt, 0, 4, stream);

    conv_kernel<<<((N_NODES + N_RELS) * DIM / 8 + 255) / 256, 256, 0, stream>>>(h, emb, Xh, embb);
    wt_kernel<<<KTOT, 256, 0, stream>>>(Wn, Wl, Wsc, Wt);
    hist_kernel<<<(N_EDGES + 255) / 256, 256, 0, stream>>>(dstv, deg);
    scanA_kernel<<<SCAN_NBLK, SCAN_BLK, 0, stream>>>(deg, excl, bsum);
    scanB_kernel<<<1, SCAN_BLK, 0, stream>>>(bsum, bbase, offsets);
    scanC_kernel<<<SCAN_NBLK, SCAN_BLK, 0, stream>>>(excl, bbase, offsets, cursor);
    scatter_kernel<<<(N_EDGES + 255) / 256, 256, 0, stream>>>(src, dstv, et, cursor, esee);
    agg_kernel<<<(N_NODES + 3) / 4, 256, 0, stream>>>(Xh, embb, norm, offsets, esee, Xa, wlcnt, wl);
    gemm_kernel<<<(N_NODES + 63) / 64, 256, 0, stream>>>(Xa, Xh, Wt, prev_h, bias, out);
    fixup_kernel<<<256, 256, 0, stream>>>(h, prev_h, We, Wsc, bias, wlcnt, wl, out);
}